// Round 4
// baseline (1332.316 us; speedup 1.0000x reference)
//
#include <hip/hip_runtime.h>

#define B_    64
#define C_    512
#define H_    32
#define WDIM  32
#define N_    1024   // H*W
#define M3C   1536   // 3*C

typedef unsigned short ushort_t;
typedef __attribute__((ext_vector_type(8))) short bf16x8;
typedef __attribute__((ext_vector_type(4))) float f32x4;
typedef __attribute__((ext_vector_type(16))) float f32x16;

#define MEMFENCE asm volatile("" ::: "memory")

// ---------------------------------------------------------------------------
// bf16 split helpers (RNE)
// ---------------------------------------------------------------------------
__device__ __forceinline__ ushort_t f2bf(float x) {
    unsigned u = __float_as_uint(x);
    unsigned r = (u + 0x7FFFu + ((u >> 16) & 1u)) >> 16;
    return (ushort_t)r;
}
__device__ __forceinline__ float bf2f(ushort_t b) {
    return __uint_as_float(((unsigned)b) << 16);
}
__device__ __forceinline__ void split_write(float v, ushort_t* __restrict__ ph,
                                            ushort_t* __restrict__ pl, size_t idx) {
    ushort_t hb = f2bf(v);
    ph[idx] = hb;
    pl[idx] = f2bf(v - bf2f(hb));
}

// async global->LDS, 16B per lane (dst = wave-uniform base + lane*16)
__device__ __forceinline__ void gld16(const void* g, void* l) {
    __builtin_amdgcn_global_load_lds((const __attribute__((address_space(1))) unsigned int*)g,
                                     (__attribute__((address_space(3))) unsigned int*)l,
                                     16, 0, 0);
}

// ---------------------------------------------------------------------------
// pos[c, h*W+w] = rel_h[c,h] + rel_w[c,w]   (fp32)
// ---------------------------------------------------------------------------
__global__ __launch_bounds__(256) void pos_kernel(const float* __restrict__ rel_h,
                                                  const float* __restrict__ rel_w,
                                                  float* __restrict__ pos) {
    int idx = blockIdx.x * 256 + threadIdx.x;
    if (idx >= C_ * N_) return;
    int c = idx >> 10;
    int n = idx & (N_ - 1);
    int h = n >> 5;
    int w = n & (WDIM - 1);
    pos[idx] = rel_h[c * H_ + h] + rel_w[c * WDIM + w];
}

// ---------------------------------------------------------------------------
// fp32 GEMM, both operands k-major: D[m][n] = sum_k A[k][m] * B[k][n]
// (used once for M = Wq^T Wk and r = Wq^T pos; tiny)
// ---------------------------------------------------------------------------
__global__ __launch_bounds__(256) void mmT_f32(const float* __restrict__ A, int lda,
                                               const float* __restrict__ B, int ldb,
                                               float* __restrict__ D, int ldd, int K) {
    __shared__ float As[16][64];
    __shared__ float Bs[16][64];
    const int m0 = blockIdx.y * 64;
    const int n0 = blockIdx.x * 64;
    const int tx = threadIdx.x, ty = threadIdx.y;
    const int tid = ty * 16 + tx;
    float acc[4][4] = {};
    for (int k0 = 0; k0 < K; k0 += 16) {
        #pragma unroll
        for (int t = 0; t < 4; ++t) {
            int e = tid + t * 256;
            int j = e >> 6, i = e & 63;
            As[j][i] = A[(size_t)(k0 + j) * lda + m0 + i];
            Bs[j][i] = B[(size_t)(k0 + j) * ldb + n0 + i];
        }
        __syncthreads();
        #pragma unroll
        for (int kk = 0; kk < 16; ++kk) {
            float a[4], bb[4];
            #pragma unroll
            for (int i = 0; i < 4; ++i) a[i]  = As[kk][ty * 4 + i];
            #pragma unroll
            for (int j = 0; j < 4; ++j) bb[j] = Bs[kk][tx * 4 + j];
            #pragma unroll
            for (int i = 0; i < 4; ++i)
                #pragma unroll
                for (int j = 0; j < 4; ++j)
                    acc[i][j] += a[i] * bb[j];
        }
        __syncthreads();
    }
    #pragma unroll
    for (int i = 0; i < 4; ++i)
        #pragma unroll
        for (int j = 0; j < 4; ++j)
            D[(size_t)(m0 + ty * 4 + i) * ldd + n0 + tx * 4 + j] = acc[i][j];
}

// ---------------------------------------------------------------------------
// F = [M ; Wv] split into bf16 hi/lo planes, natural [o][c] layout (k=c inner)
// ---------------------------------------------------------------------------
__global__ __launch_bounds__(256) void f_split(const float* __restrict__ Mtmp,
                                               const float* __restrict__ Wm,
                                               ushort_t* __restrict__ Fh,
                                               ushort_t* __restrict__ Fl) {
    int idx = blockIdx.x * 256 + threadIdx.x;
    if (idx >= 1024 * C_) return;
    int o = idx >> 9;
    int c = idx & (C_ - 1);
    float v = (o < 512) ? Mtmp[idx] : Wm[(size_t)(512 + o) * C_ + c];
    split_write(v, Fh, Fl, idx);
}

// ---------------------------------------------------------------------------
// transpose+split: src[C_][N_] fp32 -> dst hi/lo planes [N_][C_] bf16
// ---------------------------------------------------------------------------
__global__ __launch_bounds__(256) void xT_split(const float* __restrict__ x,
                                                ushort_t* __restrict__ xh,
                                                ushort_t* __restrict__ xl) {
    __shared__ float t[32][33];
    const int bl = blockIdx.z;
    const int c0 = blockIdx.y * 32;
    const int n0 = blockIdx.x * 32;
    const float* xb = x + (size_t)bl * C_ * N_;
    ushort_t* xhb = xh + (size_t)bl * N_ * C_;
    ushort_t* xlb = xl + (size_t)bl * N_ * C_;
    const int tx = threadIdx.x & 31, ty = threadIdx.x >> 5;
    #pragma unroll
    for (int r = 0; r < 4; ++r)
        t[ty + r * 8][tx] = xb[(size_t)(c0 + ty + r * 8) * N_ + n0 + tx];
    __syncthreads();
    #pragma unroll
    for (int r = 0; r < 4; ++r) {
        float v = t[tx][ty + r * 8];
        size_t o = (size_t)(n0 + ty + r * 8) * C_ + c0 + tx;
        split_write(v, xhb, xlb, o);
    }
}

// ===========================================================================
// 256x256 GEMM, 8 waves (2x4), wave tile 128x64, BK=32, 32x32x16 MFMA.
// LDS: [2 buf][planes][2 half][128 rows x 32 k], 16B-chunk XOR swizzle
//   chunk' = chunk ^ ((row>>1)&3), staged via global_load_lds with
//   pre-swizzled per-lane SOURCE addresses (linear LDS dest).
// Counted-vmcnt pipeline (T4): tile t+1's 8 (or 6) loads are issued at the
// end of tile t-1; top-of-tile wait is vmcnt(#loads-in-flight) so the next
// tile's loads stay in flight across the whole compute body; vmcnt(0) only
// on the final tile. 2 raw barriers per tile.
// HARDENING: explicit lgkmcnt(0) + sched_barrier(0) before the 2nd barrier
// (all this wave's ds_reads complete before any wave may overwrite the
// buffer — hipcc can otherwise sink the MFMA uses + their waits past the
// raw s_barrier, rule #18); empty memory-clobber asm after each barrier
// (raw s_barrier is not a compiler memory fence).
// C layout (32x32x16): col = lane&31 (B side), row = (reg&3)+8*(reg>>2)+
// 4*(lane>>5) (A side)  [HW-verified m74/m101].
// ===========================================================================

// ---------------------------------------------------------------------------
// G1: y[o][n] = sum_c F[o][c] x[c][n],  o in [0,1024)
//     o<512  -> t: written transposed+split  tT[n][o]
//     o>=512 -> v: written natural+split     v[c][m]
// ---------------------------------------------------------------------------
__global__ __launch_bounds__(512, 2) void g1_mfma(const ushort_t* __restrict__ Fh_,
                                                  const ushort_t* __restrict__ Fl_,
                                                  const ushort_t* __restrict__ xTh_,
                                                  const ushort_t* __restrict__ xTl_,
                                                  ushort_t* __restrict__ tTh_,
                                                  ushort_t* __restrict__ tTl_,
                                                  ushort_t* __restrict__ vh_,
                                                  ushort_t* __restrict__ vl_) {
    __shared__ ushort_t lds[2][4][2][4096];   // [buf][Ah,Al,Bh,Bl][half][8KB]
    const int bl = blockIdx.z;
    const int n0 = blockIdx.x * 256;
    const int m0 = blockIdx.y * 256;
    const char* Ah = (const char*)Fh_;
    const char* Al = (const char*)Fl_;
    const char* Bh = (const char*)(xTh_ + (size_t)bl * N_ * C_);
    const char* Bl = (const char*)(xTl_ + (size_t)bl * N_ * C_);

    const int tid = threadIdx.x;
    const int lane = tid & 63, wid = tid >> 6;
    const int wr = wid >> 2, wc = wid & 3;
    const int l31 = lane & 31, l5 = lane >> 5;
    const int swz4 = (l31 >> 1) & 3;
    const int chk0 = ((l5)     ^ swz4) << 3;   // ks=0 chunk offset (ushorts)
    const int chk1 = ((2 | l5) ^ swz4) << 3;   // ks=1
    const int srow = tid >> 2;
    const int toff = srow * 1024 + (((tid & 3) ^ ((srow >> 1) & 3)) << 4);
    const int ldst = wid * 512;

    f32x16 acc[4][2] = {};

#define G1_ISSUE(buf, kb) \
    gld16(Ah + (size_t)(m0)       * 1024 + (kb) + toff, &lds[buf][0][0][ldst]); \
    gld16(Ah + (size_t)(m0 + 128) * 1024 + (kb) + toff, &lds[buf][0][1][ldst]); \
    gld16(Al + (size_t)(m0)       * 1024 + (kb) + toff, &lds[buf][1][0][ldst]); \
    gld16(Al + (size_t)(m0 + 128) * 1024 + (kb) + toff, &lds[buf][1][1][ldst]); \
    gld16(Bh + (size_t)(n0)       * 1024 + (kb) + toff, &lds[buf][2][0][ldst]); \
    gld16(Bh + (size_t)(n0 + 128) * 1024 + (kb) + toff, &lds[buf][2][1][ldst]); \
    gld16(Bl + (size_t)(n0)       * 1024 + (kb) + toff, &lds[buf][3][0][ldst]); \
    gld16(Bl + (size_t)(n0 + 128) * 1024 + (kb) + toff, &lds[buf][3][1][ldst]);

    G1_ISSUE(0, 0);
    G1_ISSUE(1, 64);
    int cur = 0;
    for (int t = 0; t < 16; ++t) {
        if (t + 1 < 16) asm volatile("s_waitcnt vmcnt(8)" ::: "memory");
        else            asm volatile("s_waitcnt vmcnt(0)" ::: "memory");
        __builtin_amdgcn_s_barrier();
        MEMFENCE;
        bf16x8 bh[2][2], bo[2][2];
        #pragma unroll
        for (int j = 0; j < 2; ++j) {
            int br = ((wc & 1) * 64 + j * 32 + l31) * 32;
            bh[j][0] = *(const bf16x8*)&lds[cur][2][wc >> 1][br + chk0];
            bh[j][1] = *(const bf16x8*)&lds[cur][2][wc >> 1][br + chk1];
            bo[j][0] = *(const bf16x8*)&lds[cur][3][wc >> 1][br + chk0];
            bo[j][1] = *(const bf16x8*)&lds[cur][3][wc >> 1][br + chk1];
        }
        #pragma unroll
        for (int i = 0; i < 4; ++i) {
            int ar = (i * 32 + l31) * 32;
            bf16x8 ah0 = *(const bf16x8*)&lds[cur][0][wr][ar + chk0];
            bf16x8 ah1 = *(const bf16x8*)&lds[cur][0][wr][ar + chk1];
            bf16x8 al0 = *(const bf16x8*)&lds[cur][1][wr][ar + chk0];
            bf16x8 al1 = *(const bf16x8*)&lds[cur][1][wr][ar + chk1];
            __builtin_amdgcn_s_setprio(1);
            #pragma unroll
            for (int j = 0; j < 2; ++j) {
                acc[i][j] = __builtin_amdgcn_mfma_f32_32x32x16_bf16(ah0, bh[j][0], acc[i][j], 0,0,0);
                acc[i][j] = __builtin_amdgcn_mfma_f32_32x32x16_bf16(ah0, bo[j][0], acc[i][j], 0,0,0);
                acc[i][j] = __builtin_amdgcn_mfma_f32_32x32x16_bf16(al0, bh[j][0], acc[i][j], 0,0,0);
                acc[i][j] = __builtin_amdgcn_mfma_f32_32x32x16_bf16(ah1, bh[j][1], acc[i][j], 0,0,0);
                acc[i][j] = __builtin_amdgcn_mfma_f32_32x32x16_bf16(ah1, bo[j][1], acc[i][j], 0,0,0);
                acc[i][j] = __builtin_amdgcn_mfma_f32_32x32x16_bf16(al1, bh[j][1], acc[i][j], 0,0,0);
            }
            __builtin_amdgcn_s_setprio(0);
        }
        asm volatile("s_waitcnt lgkmcnt(0)" ::: "memory");
        __builtin_amdgcn_sched_barrier(0);
        __builtin_amdgcn_s_barrier();
        MEMFENCE;
        if (t + 2 < 16) { G1_ISSUE(cur, (t + 2) * 64); }
        cur ^= 1;
    }
#undef G1_ISSUE

    if (m0 < 512) {
        // t region: write transposed split planes tT[n][o], stride C_
        ushort_t* th = tTh_ + (size_t)bl * N_ * C_;
        ushort_t* tl = tTl_ + (size_t)bl * N_ * C_;
        #pragma unroll
        for (int i = 0; i < 4; ++i)
            #pragma unroll
            for (int j = 0; j < 2; ++j) {
                int n = n0 + wc * 64 + j * 32 + l31;
                #pragma unroll
                for (int q = 0; q < 4; ++q) {
                    int o = m0 + wr * 128 + i * 32 + q * 8 + l5 * 4;
                    ushort4 h4, l4;
                    ushort_t hb;
                    float v0 = acc[i][j][q*4+0], v1 = acc[i][j][q*4+1];
                    float v2 = acc[i][j][q*4+2], v3 = acc[i][j][q*4+3];
                    hb = f2bf(v0); h4.x = hb; l4.x = f2bf(v0 - bf2f(hb));
                    hb = f2bf(v1); h4.y = hb; l4.y = f2bf(v1 - bf2f(hb));
                    hb = f2bf(v2); h4.z = hb; l4.z = f2bf(v2 - bf2f(hb));
                    hb = f2bf(v3); h4.w = hb; l4.w = f2bf(v3 - bf2f(hb));
                    *reinterpret_cast<ushort4*>(&th[(size_t)n * C_ + o]) = h4;
                    *reinterpret_cast<ushort4*>(&tl[(size_t)n * C_ + o]) = l4;
                }
            }
    } else {
        // v region: natural split planes v[c][m], stride N_
        ushort_t* vh = vh_ + (size_t)bl * C_ * N_;
        ushort_t* vl = vl_ + (size_t)bl * C_ * N_;
        #pragma unroll
        for (int i = 0; i < 4; ++i)
            #pragma unroll
            for (int j = 0; j < 2; ++j) {
                int m = n0 + wc * 64 + j * 32 + l31;
                #pragma unroll
                for (int q = 0; q < 4; ++q) {
                    int cb = m0 - 512 + wr * 128 + i * 32 + q * 8 + l5 * 4;
                    #pragma unroll
                    for (int rr = 0; rr < 4; ++rr) {
                        float v = acc[i][j][q*4+rr];
                        ushort_t hb = f2bf(v);
                        vh[(size_t)(cb + rr) * N_ + m] = hb;
                        vl[(size_t)(cb + rr) * N_ + m] = f2bf(v - bf2f(hb));
                    }
                }
            }
    }
}

// ---------------------------------------------------------------------------
// G2: S[n][m] = sum_{k<1024} A[n][k]*B[m][k];  A=[xT|rT], B=[tT|xT] (split)
// ---------------------------------------------------------------------------
__global__ __launch_bounds__(512, 2) void g2_mfma(const ushort_t* __restrict__ xTh_,
                                                  const ushort_t* __restrict__ xTl_,
                                                  const ushort_t* __restrict__ rTh_,
                                                  const ushort_t* __restrict__ rTl_,
                                                  const ushort_t* __restrict__ tTh_,
                                                  const ushort_t* __restrict__ tTl_,
                                                  float* __restrict__ S) {
    __shared__ ushort_t lds[2][4][2][4096];
    const int bl = blockIdx.z;
    const int m0 = blockIdx.x * 256;
    const int n0 = blockIdx.y * 256;
    const char* xh = (const char*)(xTh_ + (size_t)bl * N_ * C_);
    const char* xl = (const char*)(xTl_ + (size_t)bl * N_ * C_);
    const char* th = (const char*)(tTh_ + (size_t)bl * N_ * C_);
    const char* tl = (const char*)(tTl_ + (size_t)bl * N_ * C_);
    const char* rh = (const char*)rTh_;
    const char* rl = (const char*)rTl_;

    const int tid = threadIdx.x;
    const int lane = tid & 63, wid = tid >> 6;
    const int wr = wid >> 2, wc = wid & 3;
    const int l31 = lane & 31, l5 = lane >> 5;
    const int swz4 = (l31 >> 1) & 3;
    const int chk0 = ((l5)     ^ swz4) << 3;
    const int chk1 = ((2 | l5) ^ swz4) << 3;
    const int srow = tid >> 2;
    const int toff = srow * 1024 + (((tid & 3) ^ ((srow >> 1) & 3)) << 4);
    const int ldst = wid * 512;

    f32x16 acc[4][2] = {};

#define G2_ISSUE(buf, pAh, pAl, pBh, pBl, kb) \
    gld16(pAh + (size_t)(n0)       * 1024 + (kb) + toff, &lds[buf][0][0][ldst]); \
    gld16(pAh + (size_t)(n0 + 128) * 1024 + (kb) + toff, &lds[buf][0][1][ldst]); \
    gld16(pAl + (size_t)(n0)       * 1024 + (kb) + toff, &lds[buf][1][0][ldst]); \
    gld16(pAl + (size_t)(n0 + 128) * 1024 + (kb) + toff, &lds[buf][1][1][ldst]); \
    gld16(pBh + (size_t)(m0)       * 1024 + (kb) + toff, &lds[buf][2][0][ldst]); \
    gld16(pBh + (size_t)(m0 + 128) * 1024 + (kb) + toff, &lds[buf][2][1][ldst]); \
    gld16(pBl + (size_t)(m0)       * 1024 + (kb) + toff, &lds[buf][3][0][ldst]); \
    gld16(pBl + (size_t)(m0 + 128) * 1024 + (kb) + toff, &lds[buf][3][1][ldst]);

    G2_ISSUE(0, xh, xl, th, tl, 0);
    G2_ISSUE(1, xh, xl, th, tl, 64);
    int cur = 0;
    for (int t = 0; t < 32; ++t) {
        if (t + 1 < 32) asm volatile("s_waitcnt vmcnt(8)" ::: "memory");
        else            asm volatile("s_waitcnt vmcnt(0)" ::: "memory");
        __builtin_amdgcn_s_barrier();
        MEMFENCE;
        bf16x8 bh[2][2], bo[2][2];
        #pragma unroll
        for (int j = 0; j < 2; ++j) {
            int br = ((wc & 1) * 64 + j * 32 + l31) * 32;
            bh[j][0] = *(const bf16x8*)&lds[cur][2][wc >> 1][br + chk0];
            bh[j][1] = *(const bf16x8*)&lds[cur][2][wc >> 1][br + chk1];
            bo[j][0] = *(const bf16x8*)&lds[cur][3][wc >> 1][br + chk0];
            bo[j][1] = *(const bf16x8*)&lds[cur][3][wc >> 1][br + chk1];
        }
        #pragma unroll
        for (int i = 0; i < 4; ++i) {
            int ar = (i * 32 + l31) * 32;
            bf16x8 ah0 = *(const bf16x8*)&lds[cur][0][wr][ar + chk0];
            bf16x8 ah1 = *(const bf16x8*)&lds[cur][0][wr][ar + chk1];
            bf16x8 al0 = *(const bf16x8*)&lds[cur][1][wr][ar + chk0];
            bf16x8 al1 = *(const bf16x8*)&lds[cur][1][wr][ar + chk1];
            __builtin_amdgcn_s_setprio(1);
            #pragma unroll
            for (int j = 0; j < 2; ++j) {
                acc[i][j] = __builtin_amdgcn_mfma_f32_32x32x16_bf16(ah0, bh[j][0], acc[i][j], 0,0,0);
                acc[i][j] = __builtin_amdgcn_mfma_f32_32x32x16_bf16(ah0, bo[j][0], acc[i][j], 0,0,0);
                acc[i][j] = __builtin_amdgcn_mfma_f32_32x32x16_bf16(al0, bh[j][0], acc[i][j], 0,0,0);
                acc[i][j] = __builtin_amdgcn_mfma_f32_32x32x16_bf16(ah1, bh[j][1], acc[i][j], 0,0,0);
                acc[i][j] = __builtin_amdgcn_mfma_f32_32x32x16_bf16(ah1, bo[j][1], acc[i][j], 0,0,0);
                acc[i][j] = __builtin_amdgcn_mfma_f32_32x32x16_bf16(al1, bh[j][1], acc[i][j], 0,0,0);
            }
            __builtin_amdgcn_s_setprio(0);
        }
        asm volatile("s_waitcnt lgkmcnt(0)" ::: "memory");
        __builtin_amdgcn_sched_barrier(0);
        __builtin_amdgcn_s_barrier();
        MEMFENCE;
        if (t + 2 < 32) {
            int s = t + 2;
            const char* pAh = (s < 16) ? xh : rh;
            const char* pAl = (s < 16) ? xl : rl;
            const char* pBh = (s < 16) ? th : xh;
            const char* pBl = (s < 16) ? tl : xl;
            int kb = (s & 15) * 64;
            G2_ISSUE(cur, pAh, pAl, pBh, pBl, kb);
        }
        cur ^= 1;
    }
#undef G2_ISSUE

    float* Sb = S + (size_t)bl * N_ * N_;
    #pragma unroll
    for (int i = 0; i < 4; ++i)
        #pragma unroll
        for (int j = 0; j < 2; ++j) {
            int m = m0 + wc * 64 + j * 32 + l31;
            #pragma unroll
            for (int q = 0; q < 4; ++q) {
                int n = n0 + wr * 128 + i * 32 + q * 8 + l5 * 4;
                #pragma unroll
                for (int rr = 0; rr < 4; ++rr)
                    Sb[(size_t)(n + rr) * N_ + m] = acc[i][j][q*4+rr];
            }
        }
}

// ---------------------------------------------------------------------------
// Row softmax (fp32 in) -> P bf16 [n][m]
// ---------------------------------------------------------------------------
__device__ __forceinline__ float waveMax(float v) {
    #pragma unroll
    for (int o = 32; o > 0; o >>= 1) v = fmaxf(v, __shfl_down(v, o));
    return v;
}
__device__ __forceinline__ float waveSum(float v) {
    #pragma unroll
    for (int o = 32; o > 0; o >>= 1) v += __shfl_down(v, o);
    return v;
}

__global__ __launch_bounds__(256) void softmax_bf16(const float* __restrict__ S,
                                                    ushort_t* __restrict__ P) {
    const float* Sr = S + (size_t)blockIdx.x * N_;
    ushort_t* Pr = P + (size_t)blockIdx.x * N_;
    const int tid = threadIdx.x;
    float4 v = reinterpret_cast<const float4*>(Sr)[tid];
    __shared__ float redm[4];
    __shared__ float reds[4];
    const int wave = tid >> 6, lane = tid & 63;

    float m = fmaxf(fmaxf(v.x, v.y), fmaxf(v.z, v.w));
    m = waveMax(m);
    if (lane == 0) redm[wave] = m;
    __syncthreads();
    m = fmaxf(fmaxf(redm[0], redm[1]), fmaxf(redm[2], redm[3]));

    v.x = __expf(v.x - m); v.y = __expf(v.y - m);
    v.z = __expf(v.z - m); v.w = __expf(v.w - m);
    float s = v.x + v.y + v.z + v.w;
    s = waveSum(s);
    if (lane == 0) reds[wave] = s;
    __syncthreads();
    s = reds[0] + reds[1] + reds[2] + reds[3];
    const float inv = 1.0f / s;
    ushort4 p;
    p.x = f2bf(v.x * inv); p.y = f2bf(v.y * inv);
    p.z = f2bf(v.z * inv); p.w = f2bf(v.w * inv);
    reinterpret_cast<ushort4*>(Pr)[tid] = p;
}

// ---------------------------------------------------------------------------
// G4: out[c][n] = sum_m v[c][m] P[n][m]   (A = v hi/lo, B = P single; 2 MFMA)
// ---------------------------------------------------------------------------
__global__ __launch_bounds__(512, 2) void g4_mfma(const ushort_t* __restrict__ vh_,
                                                  const ushort_t* __restrict__ vl_,
                                                  const ushort_t* __restrict__ P_,
                                                  float* __restrict__ out) {
    __shared__ ushort_t lds[2][3][2][4096];   // planes: Ah, Al, B
    const int bl = blockIdx.z;
    const int n0 = blockIdx.x * 256;
    const int c0 = blockIdx.y * 256;
    const char* Ah = (const char*)(vh_ + (size_t)bl * C_ * N_);
    const char* Al = (const char*)(vl_ + (size_t)bl * C_ * N_);
    const char* Bp = (const char*)(P_ + (size_t)bl * N_ * N_);

    const int tid = threadIdx.x;
    const int lane = tid & 63, wid = tid >> 6;
    const int wr = wid >> 2, wc = wid & 3;
    const int l31 = lane & 31, l5 = lane >> 5;
    const int swz4 = (l31 >> 1) & 3;
    const int chk0 = ((l5)     ^ swz4) << 3;
    const int chk1 = ((2 | l5) ^ swz4) << 3;
    const int srow = tid >> 2;
    const int toff = srow * 2048 + (((tid & 3) ^ ((srow >> 1) & 3)) << 4);
    const int ldst = wid * 512;

    f32x16 acc[4][2] = {};

#define G4_ISSUE(buf, kb) \
    gld16(Ah + (size_t)(c0)       * 2048 + (kb) + toff, &lds[buf][0][0][ldst]); \
    gld16(Ah + (size_t)(c0 + 128) * 2048 + (kb) + toff, &lds[buf][0][1][ldst]); \
    gld16(Al + (size_t)(c0)       * 2048 + (kb) + toff, &lds[buf][1][0][ldst]); \
    gld16(Al + (size_t)(c0 + 128) * 2048 + (kb) + toff, &lds[buf][1][1][ldst]); \
    gld16(Bp + (size_t)(n0)       * 2048 + (kb) + toff, &lds[buf][2][0][ldst]); \
    gld16(Bp + (size_t)(n0 + 128) * 2048 + (kb) + toff, &lds[buf][2][1][ldst]);

    G4_ISSUE(0, 0);
    G4_ISSUE(1, 64);
    int cur = 0;
    for (int t = 0; t < 32; ++t) {
        if (t + 1 < 32) asm volatile("s_waitcnt vmcnt(6)" ::: "memory");
        else            asm volatile("s_waitcnt vmcnt(0)" ::: "memory");
        __builtin_amdgcn_s_barrier();
        MEMFENCE;
        bf16x8 bf[2][2];
        #pragma unroll
        for (int j = 0; j < 2; ++j) {
            int br = ((wc & 1) * 64 + j * 32 + l31) * 32;
            bf[j][0] = *(const bf16x8*)&lds[cur][2][wc >> 1][br + chk0];
            bf[j][1] = *(const bf16x8*)&lds[cur][2][wc >> 1][br + chk1];
        }
        #pragma unroll
        for (int i = 0; i < 4; ++i) {
            int ar = (i * 32 + l31) * 32;
            bf16x8 ah0 = *(const bf16x8*)&lds[cur][0][wr][ar + chk0];
            bf16x8 ah1 = *(const bf16x8*)&lds[cur][0][wr][ar + chk1];
            bf16x8 al0 = *(const bf16x8*)&lds[cur][1][wr][ar + chk0];
            bf16x8 al1 = *(const bf16x8*)&lds[cur][1][wr][ar + chk1];
            __builtin_amdgcn_s_setprio(1);
            #pragma unroll
            for (int j = 0; j < 2; ++j) {
                acc[i][j] = __builtin_amdgcn_mfma_f32_32x32x16_bf16(ah0, bf[j][0], acc[i][j], 0,0,0);
                acc[i][j] = __builtin_amdgcn_mfma_f32_32x32x16_bf16(al0, bf[j][0], acc[i][j], 0,0,0);
                acc[i][j] = __builtin_amdgcn_mfma_f32_32x32x16_bf16(ah1, bf[j][1], acc[i][j], 0,0,0);
                acc[i][j] = __builtin_amdgcn_mfma_f32_32x32x16_bf16(al1, bf[j][1], acc[i][j], 0,0,0);
            }
            __builtin_amdgcn_s_setprio(0);
        }
        asm volatile("s_waitcnt lgkmcnt(0)" ::: "memory");
        __builtin_amdgcn_sched_barrier(0);
        __builtin_amdgcn_s_barrier();
        MEMFENCE;
        if (t + 2 < 32) { G4_ISSUE(cur, (t + 2) * 64); }
        cur ^= 1;
    }
#undef G4_ISSUE

    float* ob = out + (size_t)bl * C_ * N_;
    #pragma unroll
    for (int i = 0; i < 4; ++i)
        #pragma unroll
        for (int j = 0; j < 2; ++j) {
            int n = n0 + wc * 64 + j * 32 + l31;
            #pragma unroll
            for (int q = 0; q < 4; ++q) {
                int c = c0 + wr * 128 + i * 32 + q * 8 + l5 * 4;
                #pragma unroll
                for (int rr = 0; rr < 4; ++rr)
                    ob[(size_t)(c + rr) * N_ + n] = acc[i][j][q*4+rr];
            }
        }
}

// ---------------------------------------------------------------------------
extern "C" void kernel_launch(void* const* d_in, const int* in_sizes, int n_in,
                              void* d_out, int out_size, void* d_ws, size_t ws_size,
                              hipStream_t stream) {
    const float* x     = (const float*)d_in[0];
    const float* Wm    = (const float*)d_in[1];
    const float* rel_h = (const float*)d_in[2];
    const float* rel_w = (const float*)d_in[3];
    float* out = (float*)d_out;

    const size_t posB  = (size_t)C_ * N_ * 4;
    const size_t MtB   = (size_t)C_ * C_ * 4;
    const size_t rtB   = (size_t)C_ * N_ * 4;
    const size_t fplB  = (size_t)1024 * C_ * 2;
    const size_t rtplB = (size_t)N_ * C_ * 2;
    const size_t xtB   = (size_t)N_ * C_ * 2;
    const size_t ttB   = (size_t)N_ * C_ * 2;
    const size_t vplB  = (size_t)C_ * N_ * 2;
    const size_t sB    = (size_t)N_ * N_ * 4;
    const size_t pB    = (size_t)N_ * N_ * 2;
    const size_t per_batch = 2 * xtB + 2 * ttB + 2 * vplB + sB + pB;
    const size_t persist   = posB + MtB + rtB + 2 * fplB + 2 * rtplB;

    size_t rem = (ws_size > persist) ? (ws_size - persist) : 0;
    int chunkB = (int)(rem / per_batch);
    if (chunkB < 1)  chunkB = 1;
    if (chunkB > B_) chunkB = B_;

    char* p = (char*)d_ws;
    float*    pos  = (float*)p;    p += posB;
    float*    Mtmp = (float*)p;    p += MtB;
    float*    rtmp = (float*)p;    p += rtB;
    ushort_t* Fh   = (ushort_t*)p; p += fplB;
    ushort_t* Fl   = (ushort_t*)p; p += fplB;
    ushort_t* rTh  = (ushort_t*)p; p += rtplB;
    ushort_t* rTl  = (ushort_t*)p; p += rtplB;
    ushort_t* xTh  = (ushort_t*)p; p += (size_t)chunkB * xtB;
    ushort_t* xTl  = (ushort_t*)p; p += (size_t)chunkB * xtB;
    ushort_t* tTh  = (ushort_t*)p; p += (size_t)chunkB * ttB;
    ushort_t* tTl  = (ushort_t*)p; p += (size_t)chunkB * ttB;
    ushort_t* vh   = (ushort_t*)p; p += (size_t)chunkB * vplB;
    ushort_t* vl   = (ushort_t*)p; p += (size_t)chunkB * vplB;
    float*    S    = (float*)p;    p += (size_t)chunkB * sB;
    ushort_t* P    = (ushort_t*)p; p += (size_t)chunkB * pB;

    dim3 blk16(16, 16);
    pos_kernel<<<(C_ * N_ + 255) / 256, 256, 0, stream>>>(rel_h, rel_w, pos);
    mmT_f32<<<dim3(C_ / 64, C_ / 64), blk16, 0, stream>>>(Wm, C_, Wm + (size_t)C_ * C_, C_,
                                                          Mtmp, C_, C_);
    mmT_f32<<<dim3(N_ / 64, C_ / 64), blk16, 0, stream>>>(Wm, C_, pos, N_, rtmp, N_, C_);
    f_split<<<(1024 * C_ + 255) / 256, 256, 0, stream>>>(Mtmp, Wm, Fh, Fl);
    xT_split<<<dim3(N_ / 32, C_ / 32, 1), 256, 0, stream>>>(rtmp, rTh, rTl);

    for (int b0 = 0; b0 < B_; b0 += chunkB) {
        int nb = (b0 + chunkB <= B_) ? chunkB : (B_ - b0);
        const float* x_b   = x   + (size_t)b0 * C_ * N_;
        float*       out_b = out + (size_t)b0 * C_ * N_;
        xT_split<<<dim3(N_ / 32, C_ / 32, nb), 256, 0, stream>>>(x_b, xTh, xTl);
        g1_mfma<<<dim3(4, 4, nb), 512, 0, stream>>>(Fh, Fl, xTh, xTl, tTh, tTl, vh, vl);
        g2_mfma<<<dim3(4, 4, nb), 512, 0, stream>>>(xTh, xTl, rTh, rTl, tTh, tTl, S);
        softmax_bf16<<<nb * N_, 256, 0, stream>>>(S, P);
        g4_mfma<<<dim3(4, 2, nb), 512, 0, stream>>>(vh, vl, P, out_b);
    }
}